// Round 7
// baseline (664.534 us; speedup 1.0000x reference)
//
#include <hip/hip_runtime.h>
#include <math.h>

static constexpr int B_ = 8, C_ = 512, T_ = 2048, C3_ = 1536;
static constexpr float INV_TEMP = 1.0f / 0.07f;

typedef __attribute__((ext_vector_type(8))) short short8;
typedef __attribute__((ext_vector_type(4))) float floatx4;

__device__ __forceinline__ float b2f(unsigned short u) {
  union { unsigned int i; float f; } v; v.i = ((unsigned int)u) << 16; return v.f;
}
__device__ __forceinline__ unsigned short f2b(float f) {
  union { float f; unsigned int i; } v; v.f = f;
  const unsigned int x = v.i;
  return (unsigned short)((x + 0x7FFFu + ((x >> 16) & 1u)) >> 16);
}

// lgkm-only barrier: ds_writes must be visible, but GLOBAL LOADS STAY IN
// FLIGHT (the whole point — __syncthreads would drain vmcnt(0)).
#define LGKM_BARRIER() asm volatile("s_waitcnt lgkmcnt(0)\n\ts_barrier" ::: "memory")

// ---------------------------------------------------------------------------
// TN-form bf16 MFMA GEMM: C[m,n] = sum_k A[m,k]*B[n,k], A:[M,K] B:[N,K],
// both k-contiguous bf16. TM x 128 tile, 4 waves (2x2), wave tile (TM/2)x64,
// 16x16x32 MFMA, BK=32, 2-deep LDS ring.
// K-loop restructured AITER-style: global_load -> VGPR (2 tiles ahead),
// ds_write -> LDS (1 tile ahead), raw lgkm-barrier. The ds_write's vmcnt
// dependency is a full iteration away, so HBM latency is hidden; the barrier
// never drains global loads. XOR granule swizzle (slot = g ^ ((row>>1)&3))
// keeps both ds_write_b128 and ds_read_b128 bank-conflict-free.
// MODE 0: plain store.  MODE 2: fused softmax epilogue (fixed-max exp,
// bf16 store + atomic row-sum of ROUNDED weights into denom).
// MODE 3: row divide by rs[row] (softmax denominator application).
// ---------------------------------------------------------------------------
template<int TM, bool OUT_BF16, int MODE>
__global__ __launch_bounds__(256)
void gemm_tn(const unsigned short* __restrict__ A, const unsigned short* __restrict__ B,
             void* __restrict__ Cout, int K, int lda, int ldb, int ldc,
             long long sA, long long sB, long long sC,
             const float* __restrict__ rs, const float* __restrict__ cs,
             float* __restrict__ denom, int rcStride, float scale)
{
  constexpr int NFA = TM / 64 * 2;   // A fragments per wave (4 or 2)
  constexpr int LA  = TM / 64;       // A staging uint4 per thread (2 or 1)

  const int bz = blockIdx.z;
  A += (long long)bz * sA;
  B += (long long)bz * sB;
  if (MODE == 2) { rs += (long long)bz * rcStride; cs += (long long)bz * rcStride;
                   denom += (long long)bz * rcStride; }
  if (MODE == 3) { rs += (long long)bz * rcStride; }
  const int m0 = blockIdx.y * TM, n0 = blockIdx.x * 128;
  const int tid = threadIdx.x;
  const int w = tid >> 6, lane = tid & 63;
  const int wm = (w >> 1) * (TM / 2), wn = (w & 1) * 64;
  const int rl = lane & 15, qd = lane >> 4;

  __shared__ __align__(16) unsigned short As[2 * TM * 32];
  __shared__ __align__(16) unsigned short Bs[2 * 128 * 32];

  // --- staging maps (per thread) ---
  // A: TM=128: row=tid>>1, k-half sb=tid&1 (granules 2sb,2sb+1, 2 uint4)
  //    TM=64 : row=tid>>2, granule g=tid&3 (1 uint4)
  int wa0, wa1;
  const unsigned short* gA;
  if (TM == 128) {
    const int r = tid >> 1, sb = tid & 1, s = (r >> 1) & 3;
    wa0 = r * 32 + ((2 * sb) ^ s) * 8;
    wa1 = r * 32 + ((2 * sb + 1) ^ s) * 8;
    gA = A + (long long)(m0 + r) * lda + sb * 16;
  } else {
    const int r = tid >> 2, g = tid & 3, s = (r >> 1) & 3;
    wa0 = r * 32 + (g ^ s) * 8;
    wa1 = 0;
    gA = A + (long long)(m0 + r) * lda + g * 8;
  }
  // B: always 128x32: row=tid>>1, k-half sb=tid&1 (2 uint4)
  const int rB = tid >> 1, sbB = tid & 1, sB2 = (rB >> 1) & 3;
  const int wb0 = rB * 32 + ((2 * sbB) ^ sB2) * 8;
  const int wb1 = rB * 32 + ((2 * sbB + 1) ^ sB2) * 8;
  const unsigned short* gB = B + (long long)(n0 + rB) * ldb + sbB * 16;

  // fragment read offsets (swizzle-corrected)
  int aoff[NFA], boff[4];
  #pragma unroll
  for (int i = 0; i < NFA; ++i) {
    const int mr = wm + i * 16 + rl;
    aoff[i] = mr * 32 + ((qd ^ ((mr >> 1) & 3)) * 8);
  }
  #pragma unroll
  for (int j = 0; j < 4; ++j) {
    const int nr = wn + j * 16 + rl;
    boff[j] = nr * 32 + ((qd ^ ((nr >> 1) & 3)) * 8);
  }

  floatx4 acc[NFA][4];
  #pragma unroll
  for (int i = 0; i < NFA; ++i)
    #pragma unroll
    for (int j = 0; j < 4; ++j) acc[i][j] = 0.0f;

  uint4 ra0[LA], ra1[LA], rb0[2], rb1[2];

  auto loadg = [&](int t, uint4* ra, uint4* rb) {
    const long long ko = (long long)t * 32;
    ra[0] = *(const uint4*)(gA + ko);
    if (TM == 128) ra[1] = *(const uint4*)(gA + ko + 8);
    rb[0] = *(const uint4*)(gB + ko);
    rb[1] = *(const uint4*)(gB + ko + 8);
  };
  auto writel = [&](const uint4* ra, const uint4* rb, int bf) {
    unsigned short* as = As + bf * TM * 32;
    unsigned short* bs = Bs + bf * 128 * 32;
    *(uint4*)(as + wa0) = ra[0];
    if (TM == 128) *(uint4*)(as + wa1) = ra[1];
    *(uint4*)(bs + wb0) = rb[0];
    *(uint4*)(bs + wb1) = rb[1];
  };
  auto readfrags = [&](int bf, short8* fa, short8* fb) {
    const unsigned short* as = As + bf * TM * 32;
    const unsigned short* bs = Bs + bf * 128 * 32;
    #pragma unroll
    for (int i = 0; i < NFA; ++i) fa[i] = *(const short8*)(as + aoff[i]);
    #pragma unroll
    for (int j = 0; j < 4; ++j) fb[j] = *(const short8*)(bs + boff[j]);
  };
  auto domfma = [&](short8* fa, short8* fb) {
    #pragma unroll
    for (int i = 0; i < NFA; ++i)
      #pragma unroll
      for (int j = 0; j < 4; ++j)
        acc[i][j] = __builtin_amdgcn_mfma_f32_16x16x32_bf16(fa[i], fb[j], acc[i][j], 0, 0, 0);
  };

  const int niter = K >> 5;   // always even here (K = 512 or 2048)
  loadg(0, ra0, rb0);
  loadg(1, ra1, rb1);
  writel(ra0, rb0, 0);        // waits vmcnt for tile0 only (prologue cost)
  LGKM_BARRIER();

  for (int i = 0; i < niter; i += 2) {
    // ---- even sub-iter: compute from LDS[0] ----
    {
      short8 fa[NFA], fb[4];
      readfrags(0, fa, fb);
      writel(ra1, rb1, 1);                 // tile i+1 -> LDS[1] (vmcnt dep ~1 iter old)
      if (i + 2 < niter) loadg(i + 2, ra0, rb0);
      LGKM_BARRIER();                      // globals stay in flight
      domfma(fa, fb);
    }
    // ---- odd sub-iter: compute from LDS[1] ----
    {
      short8 fa[NFA], fb[4];
      readfrags(1, fa, fb);
      if (i + 2 < niter) {
        writel(ra0, rb0, 0);               // tile i+2 -> LDS[0]
        if (i + 3 < niter) loadg(i + 3, ra1, rb1);
        LGKM_BARRIER();
      }
      domfma(fa, fb);
    }
  }

  // epilogue: C/D layout col=lane&15, row=(lane>>4)*4+reg
  #pragma unroll
  for (int i = 0; i < NFA; ++i) {
    #pragma unroll
    for (int r = 0; r < 4; ++r) {
      const int row = m0 + wm + i * 16 + qd * 4 + r;
      float rowf = 0.f;
      if (MODE == 2) rowf = rs[row] * scale;
      if (MODE == 3) rowf = 1.0f / rs[row];
      float rsum = 0.f;
      #pragma unroll
      for (int j = 0; j < 4; ++j) {
        const int col = n0 + wn + j * 16 + rl;
        float v = acc[i][j][r];
        if (MODE == 2) {
          const float s = v * rowf * cs[col];
          const unsigned short pb = f2b(__expf(s - scale));
          rsum += b2f(pb);   // sum the ROUNDED weights
          ((unsigned short*)Cout)[(long long)bz * sC + (long long)row * ldc + col] = pb;
          continue;
        }
        if (MODE == 3) v *= rowf;
        const long long idx = (long long)bz * sC + (long long)row * ldc + col;
        if (OUT_BF16) ((unsigned short*)Cout)[idx] = f2b(v);
        else          ((float*)Cout)[idx] = v;
      }
      if (MODE == 2) {
        #pragma unroll
        for (int m = 1; m < 16; m <<= 1) rsum += __shfl_xor(rsum, m);
        if (rl == 0) atomicAdd(denom + row, rsum);
      }
    }
  }
}

// ---------------------------------------------------------------------------
// x [B,C,T] fp32 -> xT [B,T,C] bf16 (transpose-convert, 32x32 LDS tiles)
// ---------------------------------------------------------------------------
__global__ __launch_bounds__(256)
void conv_xT(const float* __restrict__ x, unsigned short* __restrict__ xT)
{
  const int b = blockIdx.z, t0 = blockIdx.x * 32, c0 = blockIdx.y * 32;
  const int tx = threadIdx.x & 31, ty = threadIdx.x >> 5;
  __shared__ float tile[32][33];
  const float* src = x + (long long)b * C_ * T_;
  #pragma unroll
  for (int r = 0; r < 4; ++r)
    tile[ty + 8 * r][tx] = src[(long long)(c0 + ty + 8 * r) * T_ + t0 + tx];
  __syncthreads();
  unsigned short* dst = xT + (long long)b * T_ * C_;
  #pragma unroll
  for (int r = 0; r < 4; ++r)
    dst[(long long)(t0 + ty + 8 * r) * C_ + c0 + tx] = f2b(tile[tx][ty + 8 * r]);
}

__global__ __launch_bounds__(256)
void conv_bf(const float* __restrict__ in, unsigned short* __restrict__ out, int n)
{
  const int i = blockIdx.x * 256 + threadIdx.x;
  if (i < n) out[i] = f2b(in[i]);
}

// ---------------------------------------------------------------------------
// Depthwise-3 (zero pad) on v channels [2C,3C): bf16 in [B,3C,T] -> v [B,C,T]
// ---------------------------------------------------------------------------
__global__ __launch_bounds__(256)
void dw_v(const unsigned short* __restrict__ qkv, const float* __restrict__ wdw,
          unsigned short* __restrict__ vout)
{
  const long long idx = (long long)blockIdx.x * 256 + threadIdx.x;  // [B*C*T)
  const int t = (int)(idx % T_);
  const long long rem = idx / T_;
  const int c = (int)(rem % C_), b = (int)(rem / C_);
  const unsigned short* src = qkv + ((long long)(b * C3_ + 2 * C_ + c)) * T_;
  const float* wp = wdw + (2 * C_ + c) * 3;
  const float xm = (t > 0)      ? b2f(src[t - 1]) : 0.f;
  const float x0 = b2f(src[t]);
  const float xp = (t < T_ - 1) ? b2f(src[t + 1]) : 0.f;
  vout[(long long)(b * C_ + c) * T_ + t] = f2b(fmaf(wp[0], xm, fmaf(wp[1], x0, wp[2] * xp)));
}

// ---------------------------------------------------------------------------
// Depthwise-3 + transpose for q (p=0) / k (p=1): [B,3C,T] -> [B,T,C] bf16
// ---------------------------------------------------------------------------
__global__ __launch_bounds__(256)
void dw_qk_t(const unsigned short* __restrict__ qkv, const float* __restrict__ wdw,
             unsigned short* __restrict__ qT, unsigned short* __restrict__ kT)
{
  const int bz = blockIdx.z, b = bz >> 1, p = bz & 1;
  const int t0 = blockIdx.x * 32, c0 = blockIdx.y * 32;
  const int tx = threadIdx.x & 31, ty = threadIdx.x >> 5;
  __shared__ float tin[32][34];   // [c][t-1 .. t+32]
  __shared__ float tout[32][33];  // [t][c]
  const int chb = b * C3_ + p * C_;
  #pragma unroll
  for (int r = 0; r < 4; ++r) {
    const int cy = ty + 8 * r;
    const unsigned short* src = qkv + (long long)(chb + c0 + cy) * T_;
    int t = t0 - 1 + tx;
    tin[cy][tx] = (t >= 0 && t < T_) ? b2f(src[t]) : 0.f;
    if (tx < 2) {
      const int t2 = t0 + 31 + tx;
      tin[cy][32 + tx] = (t2 < T_) ? b2f(src[t2]) : 0.f;
    }
  }
  __syncthreads();
  #pragma unroll
  for (int r = 0; r < 4; ++r) {
    const int cy = ty + 8 * r;
    const float* wp = wdw + (long long)(p * C_ + c0 + cy) * 3;
    tout[tx][cy] = fmaf(wp[0], tin[cy][tx], fmaf(wp[1], tin[cy][tx + 1], wp[2] * tin[cy][tx + 2]));
  }
  __syncthreads();
  unsigned short* dst = (p == 0 ? qT : kT) + (long long)b * T_ * C_;
  #pragma unroll
  for (int r = 0; r < 4; ++r)
    dst[(long long)(t0 + ty + 8 * r) * C_ + c0 + tx] = f2b(tout[ty + 8 * r][tx]);
}

// ---------------------------------------------------------------------------
// Row L2-norm stats from bf16 [B*T, C] rows: inv = 1/max(||row||,eps)
// Also zeroes denom (y==0) so no separate zero kernel is needed.
// ---------------------------------------------------------------------------
__global__ __launch_bounds__(256)
void norms_k(const unsigned short* __restrict__ qT, const unsigned short* __restrict__ kT,
             float* __restrict__ inv_nq, float* __restrict__ inv_nk,
             float* __restrict__ denom)
{
  const int wave = threadIdx.x >> 6, lane = threadIdx.x & 63;
  const long long row = (long long)blockIdx.x * 4 + wave;
  const unsigned short* src = (blockIdx.y == 0 ? qT : kT) + row * C_ + lane * 8;
  const uint4 u = *(const uint4*)src;
  float ss = 0.f;
  const unsigned int uu[4] = {u.x, u.y, u.z, u.w};
  #pragma unroll
  for (int i = 0; i < 4; ++i) {
    const float lo = b2f(uu[i] & 0xFFFF), hi = b2f(uu[i] >> 16);
    ss = fmaf(lo, lo, ss); ss = fmaf(hi, hi, ss);
  }
  #pragma unroll
  for (int m = 32; m; m >>= 1) ss += __shfl_xor(ss, m);
  if (lane == 0) {
    (blockIdx.y == 0 ? inv_nq : inv_nk)[row] = 1.f / fmaxf(sqrtf(ss), 1e-12f);
    if (blockIdx.y == 0) denom[row] = 0.f;
  }
}

// ---------------------------------------------------------------------------
// Workspace arena (bytes), ~185.3 MB (layout unchanged from R5/R6):
//  [0, 64M)    early: xT (16M) + wqkv_bf; late: av_t [B,T,C] bf16 (16M)
//  [64M,80M) qT  [80M,96M) kT  [96M,112M) vb
//  [112M,176M) attn bf16 [B,T,T] — early alias: qkv_bf (48M, dead after dw)
//  [176M,...)  wproj_bf, inv_nq, inv_nk, denom
// ---------------------------------------------------------------------------
extern "C" void kernel_launch(void* const* d_in, const int* in_sizes, int n_in,
                              void* d_out, int out_size, void* d_ws, size_t ws_size,
                              hipStream_t stream)
{
  const float* x      = (const float*)d_in[0];
  const float* w_qkv  = (const float*)d_in[1];
  const float* w_dw   = (const float*)d_in[2];
  const float* w_proj = (const float*)d_in[3];
  float* out = (float*)d_out;

  char* base = (char*)d_ws;
  unsigned short* xT      = (unsigned short*)base;                    // early
  unsigned short* wqkv_bf = (unsigned short*)(base + 16777216);       // early
  unsigned short* av_t    = (unsigned short*)base;                    // late
  char* p = base + 67108864;
  unsigned short* qT = (unsigned short*)p; p += 16777216;
  unsigned short* kT = (unsigned short*)p; p += 16777216;
  unsigned short* vb = (unsigned short*)p; p += 16777216;
  unsigned short* attn   = (unsigned short*)p;
  unsigned short* qkv_bf = (unsigned short*)p;                        // early alias
  p += 67108864;
  unsigned short* wproj_bf = (unsigned short*)p; p += 524288;
  float* inv_nq = (float*)p; p += 65536;
  float* inv_nk = (float*)p; p += 65536;
  float* denom  = (float*)p;

  const long long TC = (long long)T_ * C_, TT = (long long)T_ * T_;

  // 0) conversions
  conv_xT<<<dim3(T_ / 32, C_ / 32, B_), 256, 0, stream>>>(x, xT);
  conv_bf<<<(C3_ * C_) / 256, 256, 0, stream>>>(w_qkv, wqkv_bf, C3_ * C_);
  conv_bf<<<(C_ * C_) / 256, 256, 0, stream>>>(w_proj, wproj_bf, C_ * C_);

  // 1) qkv[b][o][t] = sum_c wqkv[o][c] * x[c][t]
  gemm_tn<128, true, 0><<<dim3(16, 12, B_), 256, 0, stream>>>(
      wqkv_bf, xT, qkv_bf, C_, C_, C_, T_,
      0LL, TC, (long long)C3_ * T_, nullptr, nullptr, nullptr, 0, 1.f);

  // 2) depthwise conv
  dw_v<<<(int)(((long long)B_ * C_ * T_) / 256), 256, 0, stream>>>(qkv_bf, w_dw, vb);
  dw_qk_t<<<dim3(T_ / 32, C_ / 32, B_ * 2), 256, 0, stream>>>(qkv_bf, w_dw, qT, kT);

  // 3) channel-L2 stats (from bf16 values) + denom zeroing
  norms_k<<<dim3((B_ * T_) / 4, 2), 256, 0, stream>>>(qT, kT, inv_nq, inv_nk, denom);

  // 4) scores + fused softmax (fixed-max exp) -> attn bf16 + denom atomics
  gemm_tn<128, true, 2><<<dim3(16, 16, B_), 256, 0, stream>>>(
      qT, kT, attn, C_, C_, C_, T_,
      TC, TC, TT, inv_nq, inv_nk, denom, T_, INV_TEMP);

  // 5) av_t[b][t][c] = (sum_s attn[t][s] * v[c][s]) / denom[t]   (TM=64)
  gemm_tn<64, true, 3><<<dim3(4, 32, B_), 256, 0, stream>>>(
      attn, vb, av_t, T_, T_, T_, C_,
      TT, (long long)C_ * T_, TC, denom, nullptr, nullptr, T_, 1.f);

  // 6) out[b][o][t] = sum_c wproj[o][c] * av_t[t][c]   (TM=64)
  gemm_tn<64, false, 0><<<dim3(16, 8, B_), 256, 0, stream>>>(
      wproj_bf, av_t, out, C_, C_, C_, T_,
      0LL, TC, (long long)C_ * T_, nullptr, nullptr, nullptr, 0, 1.f);
}

// Round 8
// 351.288 us; speedup vs baseline: 1.8917x; 1.8917x over previous
//
#include <hip/hip_runtime.h>
#include <math.h>

static constexpr int B_ = 8, C_ = 512, T_ = 2048, C3_ = 1536;
static constexpr float INV_TEMP = 1.0f / 0.07f;

typedef __attribute__((ext_vector_type(8))) short short8;
typedef __attribute__((ext_vector_type(4))) float floatx4;

__device__ __forceinline__ float b2f(unsigned short u) {
  union { unsigned int i; float f; } v; v.i = ((unsigned int)u) << 16; return v.f;
}
__device__ __forceinline__ unsigned short f2b(float f) {
  union { float f; unsigned int i; } v; v.f = f;
  const unsigned int x = v.i;
  return (unsigned short)((x + 0x7FFFu + ((x >> 16) & 1u)) >> 16);
}

// lgkm-only barrier: ds_writes must be visible; GLOBAL LOADS STAY IN FLIGHT
// (__syncthreads would lower to s_waitcnt vmcnt(0) lgkmcnt(0) + s_barrier).
#define LGKM_BARRIER() asm volatile("s_waitcnt lgkmcnt(0)\n\ts_barrier" ::: "memory")

// ---------------------------------------------------------------------------
// TN-form bf16 MFMA GEMM: C[m,n] = sum_k A[m,k]*B[n,k], A:[M,K] B:[N,K],
// both k-contiguous bf16. TM x 128 tile, 4 waves (2x2), wave tile (TM/2)x64,
// 16x16x32 MFMA, BK=32, 2-deep LDS ring, AITER-style staging:
// global_load -> named uint4 VGPRs (2 tiles ahead), ds_write (1 tile ahead),
// lgkm-only barrier. The ds_write's compiler-inserted vmcnt wait targets
// loads issued a full sub-iteration earlier -> HBM latency hidden by the
// intervening ds_reads + MFMAs + cross-wave TLP. NO pointer-passed arrays
// (R7's scratch-spill bug): every staging value is an individually named
// variable; fragment arrays are loop-local with constant indices.
// MODE 0: plain store.  MODE 2: fused softmax epilogue (fixed-max exp,
// bf16 store + atomic row-sum of ROUNDED weights into denom).
// MODE 3: row divide by rs[row] (softmax denominator application).
// ---------------------------------------------------------------------------
template<int TM, bool OUT_BF16, int MODE>
__global__ __launch_bounds__(256)
void gemm_tn(const unsigned short* __restrict__ A, const unsigned short* __restrict__ B,
             void* __restrict__ Cout, int K, int lda, int ldb, int ldc,
             long long sA, long long sB, long long sC,
             const float* __restrict__ rs, const float* __restrict__ cs,
             float* __restrict__ denom, int rcStride, float scale)
{
  constexpr int NFA = TM / 64 * 2;   // A fragments per wave (4 or 2)

  const int bz = blockIdx.z;
  A += (long long)bz * sA;
  B += (long long)bz * sB;
  if (MODE == 2) { rs += (long long)bz * rcStride; cs += (long long)bz * rcStride;
                   denom += (long long)bz * rcStride; }
  if (MODE == 3) { rs += (long long)bz * rcStride; }
  const int m0 = blockIdx.y * TM, n0 = blockIdx.x * 128;
  const int tid = threadIdx.x;
  const int w = tid >> 6, lane = tid & 63;
  const int wm = (w >> 1) * (TM / 2), wn = (w & 1) * 64;
  const int rl = lane & 15, qd = lane >> 4;

  __shared__ __align__(16) unsigned short As[2 * TM * 32];
  __shared__ __align__(16) unsigned short Bs[2 * 128 * 32];

  // --- staging maps (per thread); granule slot = g ^ ((row>>1)&3) ---
  int wa0, wa1;
  const unsigned short* gA;
  if (TM == 128) {
    const int r = tid >> 1, sb = tid & 1, s = (r >> 1) & 3;
    wa0 = r * 32 + ((2 * sb) ^ s) * 8;
    wa1 = r * 32 + ((2 * sb + 1) ^ s) * 8;
    gA = A + (long long)(m0 + r) * lda + sb * 16;
  } else {
    const int r = tid >> 2, g = tid & 3, s = (r >> 1) & 3;
    wa0 = r * 32 + (g ^ s) * 8;
    wa1 = 0;
    gA = A + (long long)(m0 + r) * lda + g * 8;
  }
  const int rB = tid >> 1, sbB = tid & 1, sB2 = (rB >> 1) & 3;
  const int wb0 = rB * 32 + ((2 * sbB) ^ sB2) * 8;
  const int wb1 = rB * 32 + ((2 * sbB + 1) ^ sB2) * 8;
  const unsigned short* gB = B + (long long)(n0 + rB) * ldb + sbB * 16;

  // fragment read offsets (swizzle-corrected)
  int aoff[NFA], boff[4];
  #pragma unroll
  for (int i = 0; i < NFA; ++i) {
    const int mr = wm + i * 16 + rl;
    aoff[i] = mr * 32 + ((qd ^ ((mr >> 1) & 3)) * 8);
  }
  #pragma unroll
  for (int j = 0; j < 4; ++j) {
    const int nr = wn + j * 16 + rl;
    boff[j] = nr * 32 + ((qd ^ ((nr >> 1) & 3)) * 8);
  }

  floatx4 acc[NFA][4];
  #pragma unroll
  for (int i = 0; i < NFA; ++i)
    #pragma unroll
    for (int j = 0; j < 4; ++j) acc[i][j] = 0.0f;

  // named staging registers — NEVER addressable
  uint4 a0_0, a0_1, b0_0, b0_1;   // set 0
  uint4 a1_0, a1_1, b1_0, b1_1;   // set 1

#define LOADG(t, SET) do {                                            \
    const long long ko_ = (long long)(t) * 32;                        \
    a##SET##_0 = *(const uint4*)(gA + ko_);                           \
    if (TM == 128) a##SET##_1 = *(const uint4*)(gA + ko_ + 8);        \
    b##SET##_0 = *(const uint4*)(gB + ko_);                           \
    b##SET##_1 = *(const uint4*)(gB + ko_ + 8);                       \
  } while (0)

#define WRITEL(SET, BF) do {                                          \
    unsigned short* as_ = As + (BF) * TM * 32;                        \
    unsigned short* bs_ = Bs + (BF) * 128 * 32;                       \
    *(uint4*)(as_ + wa0) = a##SET##_0;                                \
    if (TM == 128) *(uint4*)(as_ + wa1) = a##SET##_1;                 \
    *(uint4*)(bs_ + wb0) = b##SET##_0;                                \
    *(uint4*)(bs_ + wb1) = b##SET##_1;                                \
  } while (0)

#define READ_MFMA_PRE(BF, fa, fb) do {                                \
    const unsigned short* as_ = As + (BF) * TM * 32;                  \
    const unsigned short* bs_ = Bs + (BF) * 128 * 32;                 \
    _Pragma("unroll")                                                 \
    for (int ii_ = 0; ii_ < NFA; ++ii_) fa[ii_] = *(const short8*)(as_ + aoff[ii_]); \
    _Pragma("unroll")                                                 \
    for (int jj_ = 0; jj_ < 4; ++jj_) fb[jj_] = *(const short8*)(bs_ + boff[jj_]);   \
  } while (0)

#define DO_MFMA(fa, fb) do {                                          \
    _Pragma("unroll")                                                 \
    for (int ii_ = 0; ii_ < NFA; ++ii_)                               \
      _Pragma("unroll")                                               \
      for (int jj_ = 0; jj_ < 4; ++jj_)                               \
        acc[ii_][jj_] = __builtin_amdgcn_mfma_f32_16x16x32_bf16(fa[ii_], fb[jj_], acc[ii_][jj_], 0, 0, 0); \
  } while (0)

  const int niter = K >> 5;   // even (K = 512 or 2048)
  LOADG(0, 0);
  LOADG(1, 1);
  WRITEL(0, 0);               // waits vmcnt for set0 only (prologue)
  LGKM_BARRIER();

  for (int i = 0; i < niter; i += 2) {
    { // even sub-iter: compute LDS[0]; stage set1 -> LDS[1]; load i+2 -> set0
      short8 fa[NFA], fb[4];
      READ_MFMA_PRE(0, fa, fb);
      WRITEL(1, 1);
      if (i + 2 < niter) LOADG(i + 2, 0);
      LGKM_BARRIER();
      DO_MFMA(fa, fb);
    }
    { // odd sub-iter: compute LDS[1]; stage set0 -> LDS[0]; load i+3 -> set1
      short8 fa[NFA], fb[4];
      READ_MFMA_PRE(1, fa, fb);
      if (i + 2 < niter) {
        WRITEL(0, 0);
        if (i + 3 < niter) LOADG(i + 3, 1);
        LGKM_BARRIER();
      }
      DO_MFMA(fa, fb);
    }
  }
#undef LOADG
#undef WRITEL
#undef READ_MFMA_PRE
#undef DO_MFMA

  // epilogue: C/D layout col=lane&15, row=(lane>>4)*4+reg
  #pragma unroll
  for (int i = 0; i < NFA; ++i) {
    #pragma unroll
    for (int r = 0; r < 4; ++r) {
      const int row = m0 + wm + i * 16 + qd * 4 + r;
      float rowf = 0.f;
      if (MODE == 2) rowf = rs[row] * scale;
      if (MODE == 3) rowf = 1.0f / rs[row];
      float rsum = 0.f;
      #pragma unroll
      for (int j = 0; j < 4; ++j) {
        const int col = n0 + wn + j * 16 + rl;
        float v = acc[i][j][r];
        if (MODE == 2) {
          const float s = v * rowf * cs[col];
          const unsigned short pb = f2b(__expf(s - scale));
          rsum += b2f(pb);   // sum the ROUNDED weights
          ((unsigned short*)Cout)[(long long)bz * sC + (long long)row * ldc + col] = pb;
          continue;
        }
        if (MODE == 3) v *= rowf;
        const long long idx = (long long)bz * sC + (long long)row * ldc + col;
        if (OUT_BF16) ((unsigned short*)Cout)[idx] = f2b(v);
        else          ((float*)Cout)[idx] = v;
      }
      if (MODE == 2) {
        #pragma unroll
        for (int m = 1; m < 16; m <<= 1) rsum += __shfl_xor(rsum, m);
        if (rl == 0) atomicAdd(denom + row, rsum);
      }
    }
  }
}

// ---------------------------------------------------------------------------
// x [B,C,T] fp32 -> xT [B,T,C] bf16 (transpose-convert, 32x32 LDS tiles)
// ---------------------------------------------------------------------------
__global__ __launch_bounds__(256)
void conv_xT(const float* __restrict__ x, unsigned short* __restrict__ xT)
{
  const int b = blockIdx.z, t0 = blockIdx.x * 32, c0 = blockIdx.y * 32;
  const int tx = threadIdx.x & 31, ty = threadIdx.x >> 5;
  __shared__ float tile[32][33];
  const float* src = x + (long long)b * C_ * T_;
  #pragma unroll
  for (int r = 0; r < 4; ++r)
    tile[ty + 8 * r][tx] = src[(long long)(c0 + ty + 8 * r) * T_ + t0 + tx];
  __syncthreads();
  unsigned short* dst = xT + (long long)b * T_ * C_;
  #pragma unroll
  for (int r = 0; r < 4; ++r)
    dst[(long long)(t0 + ty + 8 * r) * C_ + c0 + tx] = f2b(tile[tx][ty + 8 * r]);
}

__global__ __launch_bounds__(256)
void conv_bf(const float* __restrict__ in, unsigned short* __restrict__ out, int n)
{
  const int i = blockIdx.x * 256 + threadIdx.x;
  if (i < n) out[i] = f2b(in[i]);
}

// ---------------------------------------------------------------------------
// Depthwise-3 (zero pad) on v channels [2C,3C): bf16 in [B,3C,T] -> v [B,C,T]
// ---------------------------------------------------------------------------
__global__ __launch_bounds__(256)
void dw_v(const unsigned short* __restrict__ qkv, const float* __restrict__ wdw,
          unsigned short* __restrict__ vout)
{
  const long long idx = (long long)blockIdx.x * 256 + threadIdx.x;  // [B*C*T)
  const int t = (int)(idx % T_);
  const long long rem = idx / T_;
  const int c = (int)(rem % C_), b = (int)(rem / C_);
  const unsigned short* src = qkv + ((long long)(b * C3_ + 2 * C_ + c)) * T_;
  const float* wp = wdw + (2 * C_ + c) * 3;
  const float xm = (t > 0)      ? b2f(src[t - 1]) : 0.f;
  const float x0 = b2f(src[t]);
  const float xp = (t < T_ - 1) ? b2f(src[t + 1]) : 0.f;
  vout[(long long)(b * C_ + c) * T_ + t] = f2b(fmaf(wp[0], xm, fmaf(wp[1], x0, wp[2] * xp)));
}

// ---------------------------------------------------------------------------
// Depthwise-3 + transpose for q (p=0) / k (p=1): [B,3C,T] -> [B,T,C] bf16
// ---------------------------------------------------------------------------
__global__ __launch_bounds__(256)
void dw_qk_t(const unsigned short* __restrict__ qkv, const float* __restrict__ wdw,
             unsigned short* __restrict__ qT, unsigned short* __restrict__ kT)
{
  const int bz = blockIdx.z, b = bz >> 1, p = bz & 1;
  const int t0 = blockIdx.x * 32, c0 = blockIdx.y * 32;
  const int tx = threadIdx.x & 31, ty = threadIdx.x >> 5;
  __shared__ float tin[32][34];   // [c][t-1 .. t+32]
  __shared__ float tout[32][33];  // [t][c]
  const int chb = b * C3_ + p * C_;
  #pragma unroll
  for (int r = 0; r < 4; ++r) {
    const int cy = ty + 8 * r;
    const unsigned short* src = qkv + (long long)(chb + c0 + cy) * T_;
    int t = t0 - 1 + tx;
    tin[cy][tx] = (t >= 0 && t < T_) ? b2f(src[t]) : 0.f;
    if (tx < 2) {
      const int t2 = t0 + 31 + tx;
      tin[cy][32 + tx] = (t2 < T_) ? b2f(src[t2]) : 0.f;
    }
  }
  __syncthreads();
  #pragma unroll
  for (int r = 0; r < 4; ++r) {
    const int cy = ty + 8 * r;
    const float* wp = wdw + (long long)(p * C_ + c0 + cy) * 3;
    tout[tx][cy] = fmaf(wp[0], tin[cy][tx], fmaf(wp[1], tin[cy][tx + 1], wp[2] * tin[cy][tx + 2]));
  }
  __syncthreads();
  unsigned short* dst = (p == 0 ? qT : kT) + (long long)b * T_ * C_;
  #pragma unroll
  for (int r = 0; r < 4; ++r)
    dst[(long long)(t0 + ty + 8 * r) * C_ + c0 + tx] = f2b(tout[ty + 8 * r][tx]);
}

// ---------------------------------------------------------------------------
// Row L2-norm stats from bf16 [B*T, C] rows: inv = 1/max(||row||,eps)
// Also zeroes denom (y==0) so no separate zero kernel is needed.
// ---------------------------------------------------------------------------
__global__ __launch_bounds__(256)
void norms_k(const unsigned short* __restrict__ qT, const unsigned short* __restrict__ kT,
             float* __restrict__ inv_nq, float* __restrict__ inv_nk,
             float* __restrict__ denom)
{
  const int wave = threadIdx.x >> 6, lane = threadIdx.x & 63;
  const long long row = (long long)blockIdx.x * 4 + wave;
  const unsigned short* src = (blockIdx.y == 0 ? qT : kT) + row * C_ + lane * 8;
  const uint4 u = *(const uint4*)src;
  float ss = 0.f;
  const unsigned int uu[4] = {u.x, u.y, u.z, u.w};
  #pragma unroll
  for (int i = 0; i < 4; ++i) {
    const float lo = b2f(uu[i] & 0xFFFF), hi = b2f(uu[i] >> 16);
    ss = fmaf(lo, lo, ss); ss = fmaf(hi, hi, ss);
  }
  #pragma unroll
  for (int m = 32; m; m >>= 1) ss += __shfl_xor(ss, m);
  if (lane == 0) {
    (blockIdx.y == 0 ? inv_nq : inv_nk)[row] = 1.f / fmaxf(sqrtf(ss), 1e-12f);
    if (blockIdx.y == 0) denom[row] = 0.f;
  }
}

// ---------------------------------------------------------------------------
// Workspace arena (bytes), ~185.3 MB (layout unchanged from R5/R6):
//  [0, 64M)    early: xT (16M) + wqkv_bf; late: av_t [B,T,C] bf16 (16M)
//  [64M,80M) qT  [80M,96M) kT  [96M,112M) vb
//  [112M,176M) attn bf16 [B,T,T] — early alias: qkv_bf (48M, dead after dw)
//  [176M,...)  wproj_bf, inv_nq, inv_nk, denom
// ---------------------------------------------------------------------------
extern "C" void kernel_launch(void* const* d_in, const int* in_sizes, int n_in,
                              void* d_out, int out_size, void* d_ws, size_t ws_size,
                              hipStream_t stream)
{
  const float* x      = (const float*)d_in[0];
  const float* w_qkv  = (const float*)d_in[1];
  const float* w_dw   = (const float*)d_in[2];
  const float* w_proj = (const float*)d_in[3];
  float* out = (float*)d_out;

  char* base = (char*)d_ws;
  unsigned short* xT      = (unsigned short*)base;                    // early
  unsigned short* wqkv_bf = (unsigned short*)(base + 16777216);       // early
  unsigned short* av_t    = (unsigned short*)base;                    // late
  char* p = base + 67108864;
  unsigned short* qT = (unsigned short*)p; p += 16777216;
  unsigned short* kT = (unsigned short*)p; p += 16777216;
  unsigned short* vb = (unsigned short*)p; p += 16777216;
  unsigned short* attn   = (unsigned short*)p;
  unsigned short* qkv_bf = (unsigned short*)p;                        // early alias
  p += 67108864;
  unsigned short* wproj_bf = (unsigned short*)p; p += 524288;
  float* inv_nq = (float*)p; p += 65536;
  float* inv_nk = (float*)p; p += 65536;
  float* denom  = (float*)p;

  const long long TC = (long long)T_ * C_, TT = (long long)T_ * T_;

  // 0) conversions
  conv_xT<<<dim3(T_ / 32, C_ / 32, B_), 256, 0, stream>>>(x, xT);
  conv_bf<<<(C3_ * C_) / 256, 256, 0, stream>>>(w_qkv, wqkv_bf, C3_ * C_);
  conv_bf<<<(C_ * C_) / 256, 256, 0, stream>>>(w_proj, wproj_bf, C_ * C_);

  // 1) qkv[b][o][t] = sum_c wqkv[o][c] * x[c][t]
  gemm_tn<128, true, 0><<<dim3(16, 12, B_), 256, 0, stream>>>(
      wqkv_bf, xT, qkv_bf, C_, C_, C_, T_,
      0LL, TC, (long long)C3_ * T_, nullptr, nullptr, nullptr, 0, 1.f);

  // 2) depthwise conv
  dw_v<<<(int)(((long long)B_ * C_ * T_) / 256), 256, 0, stream>>>(qkv_bf, w_dw, vb);
  dw_qk_t<<<dim3(T_ / 32, C_ / 32, B_ * 2), 256, 0, stream>>>(qkv_bf, w_dw, qT, kT);

  // 3) channel-L2 stats (from bf16 values) + denom zeroing
  norms_k<<<dim3((B_ * T_) / 4, 2), 256, 0, stream>>>(qT, kT, inv_nq, inv_nk, denom);

  // 4) scores + fused softmax (fixed-max exp) -> attn bf16 + denom atomics
  gemm_tn<128, true, 2><<<dim3(16, 16, B_), 256, 0, stream>>>(
      qT, kT, attn, C_, C_, C_, T_,
      TC, TC, TT, inv_nq, inv_nk, denom, T_, INV_TEMP);

  // 5) av_t[b][t][c] = (sum_s attn[t][s] * v[c][s]) / denom[t]   (TM=64)
  gemm_tn<64, true, 3><<<dim3(4, 32, B_), 256, 0, stream>>>(
      attn, vb, av_t, T_, T_, T_, C_,
      TT, (long long)C_ * T_, TC, denom, nullptr, nullptr, T_, 1.f);

  // 6) out[b][o][t] = sum_c wproj[o][c] * av_t[t][c]   (TM=64)
  gemm_tn<64, false, 0><<<dim3(16, 8, B_), 256, 0, stream>>>(
      wproj_bf, av_t, out, C_, C_, C_, T_,
      0LL, TC, (long long)C_ * T_, nullptr, nullptr, nullptr, 0, 1.f);
}